// Round 1
// baseline (2116.460 us; speedup 1.0000x reference)
//
#include <hip/hip_runtime.h>
#include <hip/hip_bf16.h>
#include <math.h>

typedef __hip_bfloat16 bf16;

#define B_    64
#define C_    1024
#define NTOK  256
#define NH    16
#define DH    64
#define J3    3072   // 3*C_

__device__ __forceinline__ float b2f(bf16 v){ return __bfloat162float(v); }
__device__ __forceinline__ bf16  f2b(float v){ return __float2bfloat16(v); }

// ---------------------------------------------------------------------------
// K1: Y[m, j] = sum_k X[b, k, s] * Wq[j, k],  m = b*256 + s,  Y stored bf16
// Tiles 64x64, BK=16, 256 threads, 4x4 microtile.
// ---------------------------------------------------------------------------
__global__ __launch_bounds__(256) void qkv_gemm(const float* __restrict__ X,
                                                const float* __restrict__ Wq,
                                                bf16* __restrict__ Y) {
    __shared__ float As[16][68];   // As[k][m]  (pad 68: 16B-aligned rows, bank-safe)
    __shared__ float Bs[16][68];   // Bs[k][j]

    const int tid = threadIdx.x;
    const int m0  = blockIdx.x * 64;   // 256 tiles
    const int j0  = blockIdx.y * 64;   // 48 tiles
    const int b   = m0 >> 8;           // 64-row tile lies within one batch
    const int s0  = m0 & 255;

    const int tx = tid & 15, ty = tid >> 4;
    float acc[4][4] = {};

    const int a_mi = tid & 63, a_k0 = tid >> 6;   // A: k = a_k0 + 4*i
    const int b_k  = tid & 15, b_j0 = tid >> 4;   // B: j = b_j0 + 16*i

    const float* Xbase = X + (size_t)b * C_ * NTOK + s0 + a_mi;

    for (int kk = 0; kk < C_; kk += 16) {
        #pragma unroll
        for (int i = 0; i < 4; i++) {
            int k = a_k0 + 4 * i;
            As[k][a_mi] = Xbase[(size_t)(kk + k) * NTOK];
        }
        #pragma unroll
        for (int i = 0; i < 4; i++) {
            int j = b_j0 + 16 * i;
            Bs[b_k][j] = Wq[(size_t)(j0 + j) * C_ + kk + b_k];
        }
        __syncthreads();
        #pragma unroll
        for (int kt = 0; kt < 16; kt++) {
            float4 av = *(const float4*)&As[kt][ty * 4];
            float4 bv = *(const float4*)&Bs[kt][tx * 4];
            const float a[4] = {av.x, av.y, av.z, av.w};
            const float bb[4] = {bv.x, bv.y, bv.z, bv.w};
            #pragma unroll
            for (int r = 0; r < 4; r++)
                #pragma unroll
                for (int c = 0; c < 4; c++)
                    acc[r][c] = fmaf(a[r], bb[c], acc[r][c]);
        }
        __syncthreads();
    }

    #pragma unroll
    for (int r = 0; r < 4; r++) {
        size_t row = (size_t)(m0 + ty * 4 + r) * J3 + j0 + tx * 4;
        #pragma unroll
        for (int c = 0; c < 4; c++) Y[row + c] = f2b(acc[r][c]);
    }
}

// ---------------------------------------------------------------------------
// K2: per-token attention. One block (256 thr) per (b, n) token.
//   RoPE(q,k) -> softmax(q over d)*0.125, softmax(k over h)
//   ctx[d][e] = sum_h k[h][d]*v[h][e];  o[h][e] = sum_d q[h][d]*ctx[d][e]
//   Oimg[b, n*4+(e>>4), (e&15)*16+h] = o  (== contiguous addr n*1024 + a)
// ---------------------------------------------------------------------------
__global__ __launch_bounds__(256) void attn(const bf16* __restrict__ Y,
                                            bf16* __restrict__ Oimg) {
    const int tid   = threadIdx.x;
    const int token = blockIdx.x;       // 0..16383
    const int b     = token >> 8;
    const int n     = token & 255;

    __shared__ float qs[NH][65], ks[NH][65], vs[NH][65];
    __shared__ float ctx[DH][DH];
    __shared__ float red[NH][16];

    // ---- load q/k/v (bf16 -> f32) ----
    const bf16* Yt = Y + (size_t)token * J3;
    #pragma unroll
    for (int i = 0; i < 12; i++) {
        int idx = tid + 256 * i;
        int h = idx / 192;
        int r = idx - h * 192;
        float val = b2f(Yt[idx]);
        if (r < 64)       qs[h][r] = val;
        else if (r < 128) ks[h][r - 64] = val;
        else              vs[h][r - 128] = val;
    }
    __syncthreads();

    // ---- RoPE (rotate-half), position = n ----
    const float pos = (float)n;
    #pragma unroll
    for (int i = 0; i < 2; i++) {
        int p = tid + 256 * i;          // 512 pairs
        int h = p >> 5, d = p & 31;
        float invf = __expf(-0.28782313662425572f * (float)d); // ln(1e4)/32
        float f = pos * invf;
        float sn, cs;
        sincosf(f, &sn, &cs);
        float q1 = qs[h][d], q2 = qs[h][d + 32];
        qs[h][d]      = q1 * cs - q2 * sn;
        qs[h][d + 32] = q2 * cs + q1 * sn;
        float k1 = ks[h][d], k2 = ks[h][d + 32];
        ks[h][d]      = k1 * cs - k2 * sn;
        ks[h][d + 32] = k2 * cs + k1 * sn;
    }
    __syncthreads();

    // ---- q softmax over d (64), * scale ----
    {
        int h = tid >> 4, i4 = tid & 15;
        float m = -1e30f;
        #pragma unroll
        for (int j = 0; j < 4; j++) m = fmaxf(m, qs[h][i4 * 4 + j]);
        red[h][i4] = m;
        __syncthreads();
        float rm = -1e30f;
        #pragma unroll
        for (int j = 0; j < 16; j++) rm = fmaxf(rm, red[h][j]);
        __syncthreads();
        float ev[4], ps = 0.f;
        #pragma unroll
        for (int j = 0; j < 4; j++) { ev[j] = __expf(qs[h][i4 * 4 + j] - rm); ps += ev[j]; }
        red[h][i4] = ps;
        __syncthreads();
        float rs = 0.f;
        #pragma unroll
        for (int j = 0; j < 16; j++) rs += red[h][j];
        float inv = 0.125f / rs;
        #pragma unroll
        for (int j = 0; j < 4; j++) qs[h][i4 * 4 + j] = ev[j] * inv;
    }

    // ---- k softmax over h (16) per d-column ----
    if (tid < 64) {
        int d = tid;
        float m = -1e30f;
        #pragma unroll
        for (int h = 0; h < 16; h++) m = fmaxf(m, ks[h][d]);
        float e[16], s = 0.f;
        #pragma unroll
        for (int h = 0; h < 16; h++) { e[h] = __expf(ks[h][d] - m); s += e[h]; }
        float inv = 1.f / s;
        #pragma unroll
        for (int h = 0; h < 16; h++) ks[h][d] = e[h] * inv;
    }
    __syncthreads();

    // ---- ctx[d][e] = sum_h k[h][d] * v[h][e] ----
    #pragma unroll
    for (int i = 0; i < 16; i++) {
        int idx = tid + 256 * i;
        int d = idx >> 6, e = idx & 63;
        float acc = 0.f;
        #pragma unroll
        for (int h = 0; h < 16; h++) acc = fmaf(ks[h][d], vs[h][e], acc);
        ctx[d][e] = acc;
    }
    __syncthreads();

    // ---- o[h][e] = sum_d q[h][d] * ctx[d][e]; store permuted+coalesced ----
    bf16* Ob = Oimg + (size_t)b * (C_ * NTOK) + (size_t)n * 1024;
    #pragma unroll
    for (int i = 0; i < 4; i++) {
        int a = tid + 256 * i;                       // a = e_hi*256 + e_lo*16 + h
        int h = a & 15;
        int e = ((a >> 4) & 15) + ((a >> 8) << 4);
        float acc = 0.f;
        #pragma unroll
        for (int d = 0; d < 64; d++) acc = fmaf(qs[h][d], ctx[d][e], acc);
        Ob[a] = f2b(acc);
    }
}

// ---------------------------------------------------------------------------
// K3: out[b, oc, s] = b_lin[oc] + sum_c Wl[oc, c] * Oimg[b, c, s]
// Per-batch GEMM M=1024, N=256, K=1024. Tiles 64x64, BK=16.
// ---------------------------------------------------------------------------
__global__ __launch_bounds__(256) void out_gemm(const bf16* __restrict__ Oimg,
                                                const float* __restrict__ Wl,
                                                const float* __restrict__ bl,
                                                float* __restrict__ out) {
    __shared__ float As[16][68];   // As[k][oc]
    __shared__ float Bs[16][68];   // Bs[k][s]

    const int tid = threadIdx.x;
    const int s0  = blockIdx.x * 64;   // 4 tiles
    const int m0  = blockIdx.y * 64;   // 16 tiles
    const int b   = blockIdx.z;        // 64

    const int tx = tid & 15, ty = tid >> 4;
    float acc[4][4] = {};

    const int a_k = tid & 15, a_m0 = tid >> 4;    // A: mi = a_m0 + 16*i
    const int b_si = tid & 63, b_k0 = tid >> 6;   // B: k = b_k0 + 4*i

    const bf16* Obase = Oimg + (size_t)b * (C_ * NTOK) + s0 + b_si;

    for (int kk = 0; kk < C_; kk += 16) {
        #pragma unroll
        for (int i = 0; i < 4; i++) {
            int mi = a_m0 + 16 * i;
            As[a_k][mi] = Wl[(size_t)(m0 + mi) * C_ + kk + a_k];
        }
        #pragma unroll
        for (int i = 0; i < 4; i++) {
            int k = b_k0 + 4 * i;
            Bs[k][b_si] = b2f(Obase[(size_t)(kk + k) * NTOK]);
        }
        __syncthreads();
        #pragma unroll
        for (int kt = 0; kt < 16; kt++) {
            float4 av = *(const float4*)&As[kt][ty * 4];
            float4 bv = *(const float4*)&Bs[kt][tx * 4];
            const float a[4] = {av.x, av.y, av.z, av.w};
            const float bb[4] = {bv.x, bv.y, bv.z, bv.w};
            #pragma unroll
            for (int r = 0; r < 4; r++)
                #pragma unroll
                for (int c = 0; c < 4; c++)
                    acc[r][c] = fmaf(a[r], bb[c], acc[r][c]);
        }
        __syncthreads();
    }

    #pragma unroll
    for (int r = 0; r < 4; r++) {
        int oc = m0 + ty * 4 + r;
        float bias = bl[oc];
        float4 v;
        v.x = acc[r][0] + bias; v.y = acc[r][1] + bias;
        v.z = acc[r][2] + bias; v.w = acc[r][3] + bias;
        *(float4*)&out[(size_t)b * (C_ * NTOK) + (size_t)oc * NTOK + s0 + tx * 4] = v;
    }
}

// ---------------------------------------------------------------------------
extern "C" void kernel_launch(void* const* d_in, const int* in_sizes, int n_in,
                              void* d_out, int out_size, void* d_ws, size_t ws_size,
                              hipStream_t stream) {
    const float* x     = (const float*)d_in[0];
    const float* w_qkv = (const float*)d_in[1];
    const float* w_lin = (const float*)d_in[2];
    const float* b_lin = (const float*)d_in[3];
    float* out = (float*)d_out;

    bf16* Y    = (bf16*)d_ws;                                   // [16384, 3072] bf16 (96 MiB)
    bf16* Oimg = (bf16*)((char*)d_ws + (size_t)16384 * J3 * 2); // [64, 1024, 256] bf16 (32 MiB)

    qkv_gemm<<<dim3(256, 48), 256, 0, stream>>>(x, w_qkv, Y);
    attn<<<16384, 256, 0, stream>>>(Y, Oimg);
    out_gemm<<<dim3(4, 16, 64), 256, 0, stream>>>(Oimg, w_lin, b_lin, out);
}

// Round 2
// 520.633 us; speedup vs baseline: 4.0652x; 4.0652x over previous
//
#include <hip/hip_runtime.h>
#include <hip/hip_bf16.h>
#include <math.h>

typedef __hip_bfloat16 hbf16;
typedef __attribute__((ext_vector_type(8))) __bf16  bf16x8;
typedef __attribute__((ext_vector_type(4))) float   f32x4;

#define C_    1024
#define NTOK  256
#define NH    16
#define J3    3072

__device__ __forceinline__ float b2f(hbf16 v){ return __bfloat162float(v); }
__device__ __forceinline__ unsigned short fbits(float v){
    return __builtin_bit_cast(unsigned short, __float2bfloat16(v));
}
__device__ __forceinline__ __bf16 to_bf(float v){
    return __builtin_bit_cast(__bf16, __float2bfloat16(v));
}

__device__ __forceinline__ void gload_lds16(const __bf16* g, __bf16* l) {
    __builtin_amdgcn_global_load_lds((const __attribute__((address_space(1))) void*)g,
                                     (__attribute__((address_space(3))) void*)l, 16, 0, 0);
}

// ---------------------------------------------------------------------------
// cvt: fp32 -> bf16 elementwise (vectorized), n4 = n/4
// ---------------------------------------------------------------------------
__global__ __launch_bounds__(256) void cvt_bf16(const float* __restrict__ in,
                                                __bf16* __restrict__ out, int n4) {
    int i = blockIdx.x * 256 + threadIdx.x;
    if (i < n4) {
        float4 v = ((const float4*)in)[i];
        ushort4 u;
        u.x = fbits(v.x); u.y = fbits(v.y); u.z = fbits(v.z); u.w = fbits(v.w);
        ((ushort4*)out)[i] = u;
    }
}

// ---------------------------------------------------------------------------
// xpose_x: X[64,1024,256] f32 -> Xt[b*256+s][k] bf16   (32x32 LDS tiles)
// grid (8 s-tiles, 32 k-tiles, 64 b), 256 threads
// ---------------------------------------------------------------------------
__global__ __launch_bounds__(256) void xpose_x(const float* __restrict__ X,
                                               __bf16* __restrict__ Xt) {
    __shared__ float t[32][36];
    const int b = blockIdx.z, k0 = blockIdx.y * 32, s0 = blockIdx.x * 32;
    const int tid = threadIdx.x;
    {
        int kl = tid >> 3, s4 = (tid & 7) * 4;
        float4 v = *(const float4*)(X + ((size_t)b << 18) + (size_t)(k0 + kl) * 256 + s0 + s4);
        t[kl][s4] = v.x; t[kl][s4 + 1] = v.y; t[kl][s4 + 2] = v.z; t[kl][s4 + 3] = v.w;
    }
    __syncthreads();
    {
        int sl = tid >> 3, k4 = (tid & 7) * 4;
        ushort4 u;
        u.x = fbits(t[k4][sl]); u.y = fbits(t[k4 + 1][sl]);
        u.z = fbits(t[k4 + 2][sl]); u.w = fbits(t[k4 + 3][sl]);
        *(ushort4*)(Xt + (size_t)(b * 256 + s0 + sl) * 1024 + k0 + k4) = u;
    }
}

// ---------------------------------------------------------------------------
// mfma_gemm<EPI>: C[m,n] = sum_k A[m,k]*B[n,k], A:[M,1024] bf16, B:[N,1024] bf16
// 128x128 tile, BK=64, 256 thr (4 waves, 2x2), 4x4 16x16x32 MFMAs per wave.
// LDS staging via global_load_lds(16B) with XOR-swizzled chunks.
// EPI=0: store C as bf16 row-major ldc=3072 (Y)
// EPI=1: store fp32 out[b,oc,s] = C[m=b*256+s, n=oc] + bias[oc]
// ---------------------------------------------------------------------------
template <int EPI>
__global__ __launch_bounds__(256) void mfma_gemm(const __bf16* __restrict__ A,
                                                 const __bf16* __restrict__ B,
                                                 void* __restrict__ Cout,
                                                 const float* __restrict__ bias) {
    __shared__ union __align__(16) {
        struct { __bf16 A[128 * 64]; __bf16 B[128 * 64]; } kl;  // 32 KB
        __bf16 stY[128][136];                                   // 34 KB
        float  stO[128][68];                                    // 34 KB
    } sm;

    const int tid  = threadIdx.x;
    const int wave = tid >> 6, lane = tid & 63;
    const int wm = wave & 1, wn = wave >> 1;
    const int m0 = blockIdx.x * 128, n0 = blockIdx.y * 128;

    // staging: lane -> (row-in-group, physical chunk); logical chunk = p ^ srow
    const int srow = lane >> 3;
    const int lchunk = (lane & 7) ^ srow;   // row&7 == srow always (groups 8-aligned)

    f32x4 acc[4][4] = {};

    for (int kk = 0; kk < 1024; kk += 64) {
        #pragma unroll
        for (int g4 = 0; g4 < 4; ++g4) {
            const int g = g4 * 4 + wave;
            const int row = g * 8 + srow;
            gload_lds16(A + (((size_t)(m0 + row)) << 10) + kk + lchunk * 8,
                        &sm.kl.A[g * 512]);
            gload_lds16(B + (((size_t)(n0 + row)) << 10) + kk + lchunk * 8,
                        &sm.kl.B[g * 512]);
        }
        __syncthreads();   // compiler drains vmcnt before barrier

        #pragma unroll
        for (int t = 0; t < 2; ++t) {
            const int chunk = t * 4 + (lane >> 4);
            bf16x8 af[4], bf[4];
            #pragma unroll
            for (int mi = 0; mi < 4; ++mi) {
                int row = wm * 64 + mi * 16 + (lane & 15);
                af[mi] = *(const bf16x8*)&sm.kl.A[row * 64 + ((chunk ^ (row & 7)) << 3)];
            }
            #pragma unroll
            for (int ni = 0; ni < 4; ++ni) {
                int row = wn * 64 + ni * 16 + (lane & 15);
                bf[ni] = *(const bf16x8*)&sm.kl.B[row * 64 + ((chunk ^ (row & 7)) << 3)];
            }
            #pragma unroll
            for (int mi = 0; mi < 4; ++mi)
                #pragma unroll
                for (int ni = 0; ni < 4; ++ni)
                    acc[mi][ni] = __builtin_amdgcn_mfma_f32_16x16x32_bf16(
                        af[mi], bf[ni], acc[mi][ni], 0, 0, 0);
        }
        __syncthreads();
    }

    const int cl = lane & 15, rq = lane >> 4;

    if (EPI == 0) {
        // ---- Y bf16 row-major, ldc = 3072 ----
        __syncthreads();
        #pragma unroll
        for (int mi = 0; mi < 4; ++mi)
            #pragma unroll
            for (int ni = 0; ni < 4; ++ni) {
                int row = wm * 64 + mi * 16 + rq * 4;
                int col = wn * 64 + ni * 16 + cl;
                #pragma unroll
                for (int j = 0; j < 4; ++j)
                    sm.stY[row + j][col] = to_bf(acc[mi][ni][j]);
            }
        __syncthreads();
        __bf16* Y = (__bf16*)Cout;
        #pragma unroll
        for (int i = 0; i < 8; ++i) {
            int cid = tid + 256 * i;
            int r = cid >> 4, c8 = (cid & 15) * 8;
            *(bf16x8*)(Y + (size_t)(m0 + r) * 3072 + n0 + c8) =
                *(const bf16x8*)&sm.stY[r][c8];
        }
    } else {
        // ---- out fp32 [b, oc, s] + bias ----
        float* out = (float*)Cout;
        const int bb = m0 >> 8;
        const int sbase = m0 & 255;
        #pragma unroll
        for (int p = 0; p < 2; ++p) {
            __syncthreads();
            if (wm == p) {
                #pragma unroll
                for (int mi = 0; mi < 4; ++mi)
                    #pragma unroll
                    for (int ni = 0; ni < 4; ++ni) {
                        int rloc = mi * 16 + rq * 4;          // 0..63 within half
                        int col  = wn * 64 + ni * 16 + cl;
                        *(f32x4*)&sm.stO[col][rloc] = acc[mi][ni];
                    }
            }
            __syncthreads();
            #pragma unroll
            for (int i = 0; i < 8; ++i) {
                int cid = tid + 256 * i;
                int ocl = cid >> 4, d4 = (cid & 15) * 4;
                f32x4 v = *(const f32x4*)&sm.stO[ocl][d4];
                float bv = bias[n0 + ocl];
                v += bv;
                *(f32x4*)(out + ((size_t)bb << 18) + ((size_t)(n0 + ocl) << 8)
                          + sbase + p * 64 + d4) = v;
            }
        }
    }
}

// ---------------------------------------------------------------------------
// attn: unchanged math; output now Ot[b*256 + s][c] bf16 (s=(e&15)*16+h, c=n*4+e_hi)
// ---------------------------------------------------------------------------
__global__ __launch_bounds__(256) void attn(const hbf16* __restrict__ Y,
                                            __bf16* __restrict__ Ot) {
    const int tid   = threadIdx.x;
    const int token = blockIdx.x;
    const int b     = token >> 8;
    const int n     = token & 255;

    __shared__ float qs[NH][65], ks[NH][65], vs[NH][65];
    __shared__ float ctx[64][64];
    __shared__ float red[NH][16];

    const hbf16* Yt = Y + (size_t)token * J3;
    #pragma unroll
    for (int i = 0; i < 12; i++) {
        int idx = tid + 256 * i;
        int h = idx / 192;
        int r = idx - h * 192;
        float val = b2f(Yt[idx]);
        if (r < 64)       qs[h][r] = val;
        else if (r < 128) ks[h][r - 64] = val;
        else              vs[h][r - 128] = val;
    }
    __syncthreads();

    const float pos = (float)n;
    #pragma unroll
    for (int i = 0; i < 2; i++) {
        int p = tid + 256 * i;
        int h = p >> 5, d = p & 31;
        float invf = __expf(-0.28782313662425572f * (float)d);
        float f = pos * invf;
        float sn, cs;
        sincosf(f, &sn, &cs);
        float q1 = qs[h][d], q2 = qs[h][d + 32];
        qs[h][d]      = q1 * cs - q2 * sn;
        qs[h][d + 32] = q2 * cs + q1 * sn;
        float k1 = ks[h][d], k2 = ks[h][d + 32];
        ks[h][d]      = k1 * cs - k2 * sn;
        ks[h][d + 32] = k2 * cs + k1 * sn;
    }
    __syncthreads();

    {
        int h = tid >> 4, i4 = tid & 15;
        float m = -1e30f;
        #pragma unroll
        for (int j = 0; j < 4; j++) m = fmaxf(m, qs[h][i4 * 4 + j]);
        red[h][i4] = m;
        __syncthreads();
        float rm = -1e30f;
        #pragma unroll
        for (int j = 0; j < 16; j++) rm = fmaxf(rm, red[h][j]);
        __syncthreads();
        float ev[4], ps = 0.f;
        #pragma unroll
        for (int j = 0; j < 4; j++) { ev[j] = __expf(qs[h][i4 * 4 + j] - rm); ps += ev[j]; }
        red[h][i4] = ps;
        __syncthreads();
        float rs = 0.f;
        #pragma unroll
        for (int j = 0; j < 16; j++) rs += red[h][j];
        float inv = 0.125f / rs;
        #pragma unroll
        for (int j = 0; j < 4; j++) qs[h][i4 * 4 + j] = ev[j] * inv;
    }

    if (tid < 64) {
        int d = tid;
        float m = -1e30f;
        #pragma unroll
        for (int h = 0; h < 16; h++) m = fmaxf(m, ks[h][d]);
        float e[16], s = 0.f;
        #pragma unroll
        for (int h = 0; h < 16; h++) { e[h] = __expf(ks[h][d] - m); s += e[h]; }
        float inv = 1.f / s;
        #pragma unroll
        for (int h = 0; h < 16; h++) ks[h][d] = e[h] * inv;
    }
    __syncthreads();

    #pragma unroll
    for (int i = 0; i < 16; i++) {
        int idx = tid + 256 * i;
        int d = idx >> 6, e = idx & 63;
        float acc = 0.f;
        #pragma unroll
        for (int h = 0; h < 16; h++) acc = fmaf(ks[h][d], vs[h][e], acc);
        ctx[d][e] = acc;
    }
    __syncthreads();

    // o[h][e], e = e_lo + 16*i; thread owns Ot row s = e_lo*16+h, cols n*4+i
    float vout[4];
    #pragma unroll
    for (int i = 0; i < 4; i++) {
        int a = tid + 256 * i;
        int h = a & 15;
        int e = ((a >> 4) & 15) + ((a >> 8) << 4);
        float acc = 0.f;
        #pragma unroll
        for (int d = 0; d < 64; d++) acc = fmaf(qs[h][d], ctx[d][e], acc);
        vout[i] = acc;
    }
    const int sth = ((tid >> 4) & 15) * 16 + (tid & 15);
    ushort4 u;
    u.x = fbits(vout[0]); u.y = fbits(vout[1]); u.z = fbits(vout[2]); u.w = fbits(vout[3]);
    *(ushort4*)(Ot + (((size_t)(b * 256 + sth)) << 10) + n * 4) = u;
}

// ---------------------------------------------------------------------------
extern "C" void kernel_launch(void* const* d_in, const int* in_sizes, int n_in,
                              void* d_out, int out_size, void* d_ws, size_t ws_size,
                              hipStream_t stream) {
    const float* x     = (const float*)d_in[0];
    const float* w_qkv = (const float*)d_in[1];
    const float* w_lin = (const float*)d_in[2];
    const float* b_lin = (const float*)d_in[3];
    float* out = (float*)d_out;

    char* ws = (char*)d_ws;
    __bf16* Y    = (__bf16*)ws;                               // 96 MiB [16384,3072]
    __bf16* XtOt = (__bf16*)(ws + (size_t)100663296);         // 32 MiB [16384,1024] (Xt then Ot)
    __bf16* Wqb  = (__bf16*)(ws + (size_t)134217728);         // 6 MiB  [3072,1024]
    __bf16* Wlb  = (__bf16*)(ws + (size_t)140509184);         // 2 MiB  [1024,1024]

    cvt_bf16<<<3072, 256, 0, stream>>>(w_qkv, Wqb, 786432);
    cvt_bf16<<<1024, 256, 0, stream>>>(w_lin, Wlb, 262144);
    xpose_x<<<dim3(8, 32, 64), 256, 0, stream>>>(x, XtOt);

    mfma_gemm<0><<<dim3(128, 24), 256, 0, stream>>>(XtOt, Wqb, (void*)Y, nullptr);
    attn<<<16384, 256, 0, stream>>>((const hbf16*)Y, XtOt);   // Xt dead; reuse as Ot
    mfma_gemm<1><<<dim3(128, 8), 256, 0, stream>>>(XtOt, Wlb, (void*)out, b_lin);
}

// Round 3
// 345.627 us; speedup vs baseline: 6.1235x; 1.5063x over previous
//
#include <hip/hip_runtime.h>
#include <hip/hip_bf16.h>
#include <math.h>

typedef __hip_bfloat16 hbf16;
typedef __attribute__((ext_vector_type(8))) __bf16    bf16x8;
typedef __attribute__((ext_vector_type(4))) float     f32x4;
typedef __attribute__((ext_vector_type(4))) _Float16  f16x4;

#define C_    1024
#define NTOK  256
#define NH    16
#define J3    3072

__device__ __forceinline__ float b2f(hbf16 v){ return __bfloat162float(v); }
__device__ __forceinline__ unsigned short fbits(float v){
    return __builtin_bit_cast(unsigned short, __float2bfloat16(v));
}
__device__ __forceinline__ __bf16 to_bf(float v){
    return __builtin_bit_cast(__bf16, __float2bfloat16(v));
}

__device__ __forceinline__ void gload_lds16(const __bf16* g, __bf16* l) {
    __builtin_amdgcn_global_load_lds((const __attribute__((address_space(1))) void*)g,
                                     (__attribute__((address_space(3))) void*)l, 16, 0, 0);
}

// ---------------------------------------------------------------------------
// cvt: fp32 -> bf16 elementwise (vectorized), n4 = n/4
// ---------------------------------------------------------------------------
__global__ __launch_bounds__(256) void cvt_bf16(const float* __restrict__ in,
                                                __bf16* __restrict__ out, int n4) {
    int i = blockIdx.x * 256 + threadIdx.x;
    if (i < n4) {
        float4 v = ((const float4*)in)[i];
        ushort4 u;
        u.x = fbits(v.x); u.y = fbits(v.y); u.z = fbits(v.z); u.w = fbits(v.w);
        ((ushort4*)out)[i] = u;
    }
}

// ---------------------------------------------------------------------------
// xpose_x: X[64,1024,256] f32 -> Xt[b*256+s][k] bf16   (32x32 LDS tiles)
// ---------------------------------------------------------------------------
__global__ __launch_bounds__(256) void xpose_x(const float* __restrict__ X,
                                               __bf16* __restrict__ Xt) {
    __shared__ float t[32][36];
    const int b = blockIdx.z, k0 = blockIdx.y * 32, s0 = blockIdx.x * 32;
    const int tid = threadIdx.x;
    {
        int kl = tid >> 3, s4 = (tid & 7) * 4;
        float4 v = *(const float4*)(X + ((size_t)b << 18) + (size_t)(k0 + kl) * 256 + s0 + s4);
        t[kl][s4] = v.x; t[kl][s4 + 1] = v.y; t[kl][s4 + 2] = v.z; t[kl][s4 + 3] = v.w;
    }
    __syncthreads();
    {
        int sl = tid >> 3, k4 = (tid & 7) * 4;
        ushort4 u;
        u.x = fbits(t[k4][sl]); u.y = fbits(t[k4 + 1][sl]);
        u.z = fbits(t[k4 + 2][sl]); u.w = fbits(t[k4 + 3][sl]);
        *(ushort4*)(Xt + (size_t)(b * 256 + s0 + sl) * 1024 + k0 + k4) = u;
    }
}

// ---------------------------------------------------------------------------
// mfma_gemm<EPI>: C[m,n] = sum_k A[m,k]*B[n,k] (both k-contiguous bf16, K=1024)
// 128x128 tile, BK=64, 4 waves, 16x16x32 MFMA. (unchanged from round 2)
// ---------------------------------------------------------------------------
template <int EPI>
__global__ __launch_bounds__(256) void mfma_gemm(const __bf16* __restrict__ A,
                                                 const __bf16* __restrict__ B,
                                                 void* __restrict__ Cout,
                                                 const float* __restrict__ bias) {
    __shared__ union __align__(16) {
        struct { __bf16 A[128 * 64]; __bf16 B[128 * 64]; } kl;
        __bf16 stY[128][136];
        float  stO[128][68];
    } sm;

    const int tid  = threadIdx.x;
    const int wave = tid >> 6, lane = tid & 63;
    const int wm = wave & 1, wn = wave >> 1;
    const int m0 = blockIdx.x * 128, n0 = blockIdx.y * 128;

    const int srow = lane >> 3;
    const int lchunk = (lane & 7) ^ srow;

    f32x4 acc[4][4] = {};

    for (int kk = 0; kk < 1024; kk += 64) {
        #pragma unroll
        for (int g4 = 0; g4 < 4; ++g4) {
            const int g = g4 * 4 + wave;
            const int row = g * 8 + srow;
            gload_lds16(A + (((size_t)(m0 + row)) << 10) + kk + lchunk * 8,
                        &sm.kl.A[g * 512]);
            gload_lds16(B + (((size_t)(n0 + row)) << 10) + kk + lchunk * 8,
                        &sm.kl.B[g * 512]);
        }
        __syncthreads();

        #pragma unroll
        for (int t = 0; t < 2; ++t) {
            const int chunk = t * 4 + (lane >> 4);
            bf16x8 af[4], bf[4];
            #pragma unroll
            for (int mi = 0; mi < 4; ++mi) {
                int row = wm * 64 + mi * 16 + (lane & 15);
                af[mi] = *(const bf16x8*)&sm.kl.A[row * 64 + ((chunk ^ (row & 7)) << 3)];
            }
            #pragma unroll
            for (int ni = 0; ni < 4; ++ni) {
                int row = wn * 64 + ni * 16 + (lane & 15);
                bf[ni] = *(const bf16x8*)&sm.kl.B[row * 64 + ((chunk ^ (row & 7)) << 3)];
            }
            #pragma unroll
            for (int mi = 0; mi < 4; ++mi)
                #pragma unroll
                for (int ni = 0; ni < 4; ++ni)
                    acc[mi][ni] = __builtin_amdgcn_mfma_f32_16x16x32_bf16(
                        af[mi], bf[ni], acc[mi][ni], 0, 0, 0);
        }
        __syncthreads();
    }

    const int cl = lane & 15, rq = lane >> 4;

    if (EPI == 0) {
        __syncthreads();
        #pragma unroll
        for (int mi = 0; mi < 4; ++mi)
            #pragma unroll
            for (int ni = 0; ni < 4; ++ni) {
                int row = wm * 64 + mi * 16 + rq * 4;
                int col = wn * 64 + ni * 16 + cl;
                #pragma unroll
                for (int j = 0; j < 4; ++j)
                    sm.stY[row + j][col] = to_bf(acc[mi][ni][j]);
            }
        __syncthreads();
        __bf16* Y = (__bf16*)Cout;
        #pragma unroll
        for (int i = 0; i < 8; ++i) {
            int cid = tid + 256 * i;
            int r = cid >> 4, c8 = (cid & 15) * 8;
            *(bf16x8*)(Y + (size_t)(m0 + r) * 3072 + n0 + c8) =
                *(const bf16x8*)&sm.stY[r][c8];
        }
    } else {
        float* out = (float*)Cout;
        const int bb = m0 >> 8;
        const int sbase = m0 & 255;
        #pragma unroll
        for (int p = 0; p < 2; ++p) {
            __syncthreads();
            if (wm == p) {
                #pragma unroll
                for (int mi = 0; mi < 4; ++mi)
                    #pragma unroll
                    for (int ni = 0; ni < 4; ++ni) {
                        int rloc = mi * 16 + rq * 4;
                        int col  = wn * 64 + ni * 16 + cl;
                        *(f32x4*)&sm.stO[col][rloc] = acc[mi][ni];
                    }
            }
            __syncthreads();
            #pragma unroll
            for (int i = 0; i < 8; ++i) {
                int cid = tid + 256 * i;
                int ocl = cid >> 4, d4 = (cid & 15) * 4;
                f32x4 v = *(const f32x4*)&sm.stO[ocl][d4];
                float bv = bias[n0 + ocl];
                v += bv;
                *(f32x4*)(out + ((size_t)bb << 18) + ((size_t)(n0 + ocl) << 8)
                          + sbase + p * 64 + d4) = v;
            }
        }
    }
}

// ---------------------------------------------------------------------------
// attn_mfma: one wave per token. o = (softmax_d(rope(q))*scale · softmax_h(rope(k))^T) · v
// S' = k·q^T via 16x16x32 bf16 MFMA; S' C-regs feed o-MFMA A-operand directly
// (C-layout row=quad*4+r,col=lane&15 reinterpreted as A[m=lane&15][k=quad*4+r]
//  gives exactly S[h=m][h'=k]). o = S·v via 16x16x16 f16 MFMA (4 N-tiles).
// Output Ot[b*256 + s][c] bf16, s=(e&15)*16+h, c=n*4+(e>>4).
// ---------------------------------------------------------------------------
__global__ __launch_bounds__(256) void attn_mfma(const __bf16* __restrict__ Y,
                                                 __bf16* __restrict__ Ot) {
    __shared__ __bf16 vst[4][1024];   // per-wave v[16][64]

    const int tid  = threadIdx.x;
    const int wave = tid >> 6, lane = tid & 63;
    const int token = blockIdx.x * 4 + wave;
    const int b = token >> 8, n = token & 255;
    const int quad = lane >> 4, m = lane & 15;
    const __bf16* Yt = Y + (size_t)token * J3;

    // ---- stage v[16][64] -> LDS (row-major, 2 wave-level 16B DMA instrs) ----
    #pragma unroll
    for (int p = 0; p < 2; ++p) {
        const int h = p * 8 + (lane >> 3), part = lane & 7;
        gload_lds16(Yt + h * 192 + 128 + part * 8, &vst[wave][p * 512]);
    }

    // ---- q,k fragments straight from global: [h=m][d = st*32 + quad*8 + j] ----
    bf16x8 qb[2], kb[2];
    #pragma unroll
    for (int st = 0; st < 2; ++st) {
        qb[st] = *(const bf16x8*)(Yt + m * 192 +      st * 32 + quad * 8);
        kb[st] = *(const bf16x8*)(Yt + m * 192 + 64 + st * 32 + quad * 8);
    }
    float qf[16], kf[16];
    #pragma unroll
    for (int st = 0; st < 2; ++st)
        #pragma unroll
        for (int j = 0; j < 8; ++j) {
            qf[st * 8 + j] = (float)qb[st][j];
            kf[st * 8 + j] = (float)kb[st][j];
        }

    // ---- RoPE: pairs (d, d+32) are lane-local (st=0 vs st=1, same j) ----
    const float fn = (float)n;
    #pragma unroll
    for (int j = 0; j < 8; ++j) {
        const float d  = (float)(quad * 8 + j);
        const float th = fn * __expf(-0.28782313662425572f * d);  // n * 10000^(-d/32)
        const float sn = __sinf(th), cn = __cosf(th);
        float a0 = qf[j], a1 = qf[8 + j];
        qf[j]     = a0 * cn - a1 * sn;
        qf[8 + j] = a1 * cn + a0 * sn;
        float b0 = kf[j], b1 = kf[8 + j];
        kf[j]     = b0 * cn - b1 * sn;
        kf[8 + j] = b1 * cn + b0 * sn;
    }

    // ---- q softmax over d (row h=m spread over lanes m, m+16, m+32, m+48) ----
    // max-free: |q| < ~10 makes fp32 exp safe (inputs ~N(0, 0.41)).
    float qe[16], ls = 0.f;
    #pragma unroll
    for (int i = 0; i < 16; ++i) { qe[i] = __expf(qf[i]); ls += qe[i]; }
    ls += __shfl_xor(ls, 16);
    ls += __shfl_xor(ls, 32);
    const float qinv = 0.125f * __builtin_amdgcn_rcpf(ls);
    bf16x8 qbh[2];
    #pragma unroll
    for (int st = 0; st < 2; ++st)
        #pragma unroll
        for (int j = 0; j < 8; ++j) qbh[st][j] = to_bf(qe[st * 8 + j] * qinv);

    // ---- k softmax over h (16-lane butterfly per d element) ----
    float ke[16], kc[16];
    #pragma unroll
    for (int i = 0; i < 16; ++i) { ke[i] = __expf(kf[i]); kc[i] = ke[i]; }
    #pragma unroll
    for (int msk = 1; msk <= 8; msk <<= 1)
        #pragma unroll
        for (int i = 0; i < 16; ++i) kc[i] += __shfl_xor(kc[i], msk);
    bf16x8 kbh[2];
    #pragma unroll
    for (int st = 0; st < 2; ++st)
        #pragma unroll
        for (int j = 0; j < 8; ++j)
            kbh[st][j] = to_bf(ke[st * 8 + j] * __builtin_amdgcn_rcpf(kc[st * 8 + j]));

    // ---- S' = k · q^T  (S'[h'][h], C-layout: row=h'=quad*4+r, col=h=m) ----
    f32x4 Sp = {0.f, 0.f, 0.f, 0.f};
    Sp = __builtin_amdgcn_mfma_f32_16x16x32_bf16(kbh[0], qbh[0], Sp, 0, 0, 0);
    Sp = __builtin_amdgcn_mfma_f32_16x16x32_bf16(kbh[1], qbh[1], Sp, 0, 0, 0);

    __syncthreads();   // drain v DMA (vmcnt) before LDS picks

#if __has_builtin(__builtin_amdgcn_mfma_f32_16x16x16f16)
    // A-frag 16x16x16: A[m][k=quad*4+j] := Sp reg j = S'[quad*4+j][m] = S[m][quad*4+j]
    f16x4 af;
    #pragma unroll
    for (int r = 0; r < 4; ++r) af[r] = (_Float16)Sp[r];
    f32x4 o4[4];
    #pragma unroll
    for (int tile = 0; tile < 4; ++tile) {
        f16x4 bv;
        #pragma unroll
        for (int j = 0; j < 4; ++j)
            bv[j] = (_Float16)(float)vst[wave][(quad * 4 + j) * 64 + tile * 16 + m];
        f32x4 z = {0.f, 0.f, 0.f, 0.f};
        o4[tile] = __builtin_amdgcn_mfma_f32_16x16x16f16(af, bv, z, 0, 0, 0);
    }
#else
    // Fallback: padded-K 16x16x32 bf16. Gather S[m][k], k=quad*8+j (quads 0,1), via shfl.
    bf16x8 a2;
    #pragma unroll
    for (int j = 0; j < 8; ++j) {
        int k = quad * 8 + j;                 // meaningful for quad<2
        int src = ((k & 15) >> 2) * 16 + m;   // lane holding S'[k][m]
        float v = __shfl(Sp[k & 3], src, 64);
        a2[j] = (quad < 2) ? to_bf(v) : to_bf(0.f);
    }
    f32x4 o4[4];
    #pragma unroll
    for (int tile = 0; tile < 4; ++tile) {
        bf16x8 bv;
        #pragma unroll
        for (int j = 0; j < 8; ++j) {
            int k = quad * 8 + j;
            int kk = (k < 16) ? k : 0;        // clamp; A is 0 there anyway
            bv[j] = vst[wave][kk * 64 + tile * 16 + m];
        }
        f32x4 z = {0.f, 0.f, 0.f, 0.f};
        o4[tile] = __builtin_amdgcn_mfma_f32_16x16x32_bf16(a2, bv, z, 0, 0, 0);
    }
#endif

    // ---- store: o[h=quad*4+r][e=tile*16+m] -> Ot[(b*256 + m*16+quad*4+r)][n*4+tile]
    __bf16* Ob = Ot + (((size_t)(b * 256)) << 10) + n * 4;
    #pragma unroll
    for (int r = 0; r < 4; ++r) {
        const int sth = m * 16 + quad * 4 + r;
        ushort4 u;
        u.x = fbits(o4[0][r]); u.y = fbits(o4[1][r]);
        u.z = fbits(o4[2][r]); u.w = fbits(o4[3][r]);
        *(ushort4*)(Ob + ((size_t)sth << 10)) = u;
    }
}

// ---------------------------------------------------------------------------
extern "C" void kernel_launch(void* const* d_in, const int* in_sizes, int n_in,
                              void* d_out, int out_size, void* d_ws, size_t ws_size,
                              hipStream_t stream) {
    const float* x     = (const float*)d_in[0];
    const float* w_qkv = (const float*)d_in[1];
    const float* w_lin = (const float*)d_in[2];
    const float* b_lin = (const float*)d_in[3];
    float* out = (float*)d_out;

    char* ws = (char*)d_ws;
    __bf16* Y    = (__bf16*)ws;                               // 96 MiB [16384,3072]
    __bf16* XtOt = (__bf16*)(ws + (size_t)100663296);         // 32 MiB [16384,1024] (Xt then Ot)
    __bf16* Wqb  = (__bf16*)(ws + (size_t)134217728);         // 6 MiB  [3072,1024]
    __bf16* Wlb  = (__bf16*)(ws + (size_t)140509184);         // 2 MiB  [1024,1024]

    cvt_bf16<<<3072, 256, 0, stream>>>(w_qkv, Wqb, 786432);
    cvt_bf16<<<1024, 256, 0, stream>>>(w_lin, Wlb, 262144);
    xpose_x<<<dim3(8, 32, 64), 256, 0, stream>>>(x, XtOt);

    mfma_gemm<0><<<dim3(128, 24), 256, 0, stream>>>(XtOt, Wqb, (void*)Y, nullptr);
    attn_mfma<<<4096, 256, 0, stream>>>(Y, XtOt);             // Xt dead; reuse as Ot
    mfma_gemm<1><<<dim3(128, 8), 256, 0, stream>>>(XtOt, Wlb, (void*)out, b_lin);
}

// Round 4
// 334.971 us; speedup vs baseline: 6.3183x; 1.0318x over previous
//
#include <hip/hip_runtime.h>
#include <hip/hip_bf16.h>
#include <math.h>

typedef __hip_bfloat16 hbf16;
typedef __attribute__((ext_vector_type(8))) __bf16    bf16x8;
typedef __attribute__((ext_vector_type(4))) float     f32x4;
typedef __attribute__((ext_vector_type(4))) _Float16  f16x4;
typedef __attribute__((ext_vector_type(8))) unsigned short u16x8;

#define C_    1024
#define NTOK  256
#define NH    16
#define J3    3072

__device__ __forceinline__ unsigned short fbits(float v){
    return __builtin_bit_cast(unsigned short, __float2bfloat16(v));
}
__device__ __forceinline__ __bf16 to_bf(float v){
    return __builtin_bit_cast(__bf16, __float2bfloat16(v));
}

__device__ __forceinline__ void gload_lds16(const __bf16* g, __bf16* l) {
    __builtin_amdgcn_global_load_lds((const __attribute__((address_space(1))) void*)g,
                                     (__attribute__((address_space(3))) void*)l, 16, 0, 0);
}

// ---------------------------------------------------------------------------
// cvt both weight tensors in one launch. blocks [0,3072) -> w_qkv, rest -> w_lin
// ---------------------------------------------------------------------------
__global__ __launch_bounds__(256) void cvt_w(const float* __restrict__ wq,
                                             __bf16* __restrict__ wqo,
                                             const float* __restrict__ wl,
                                             __bf16* __restrict__ wlo) {
    const float* in; __bf16* out; int i;
    if (blockIdx.x < 3072) { in = wq; out = wqo; i = blockIdx.x * 256 + threadIdx.x; }
    else                   { in = wl; out = wlo; i = (blockIdx.x - 3072) * 256 + threadIdx.x; }
    float4 v = ((const float4*)in)[i];
    ushort4 u;
    u.x = fbits(v.x); u.y = fbits(v.y); u.z = fbits(v.z); u.w = fbits(v.w);
    ((ushort4*)out)[i] = u;
}

// ---------------------------------------------------------------------------
// xpose_x: X[64,1024,256] f32 -> Xt[b*256+s][k] bf16   (32x32 LDS tiles)
// ---------------------------------------------------------------------------
__global__ __launch_bounds__(256) void xpose_x(const float* __restrict__ X,
                                               __bf16* __restrict__ Xt) {
    __shared__ float t[32][36];
    const int b = blockIdx.z, k0 = blockIdx.y * 32, s0 = blockIdx.x * 32;
    const int tid = threadIdx.x;
    {
        int kl = tid >> 3, s4 = (tid & 7) * 4;
        float4 v = *(const float4*)(X + ((size_t)b << 18) + (size_t)(k0 + kl) * 256 + s0 + s4);
        t[kl][s4] = v.x; t[kl][s4 + 1] = v.y; t[kl][s4 + 2] = v.z; t[kl][s4 + 3] = v.w;
    }
    __syncthreads();
    {
        int sl = tid >> 3, k4 = (tid & 7) * 4;
        ushort4 u;
        u.x = fbits(t[k4][sl]); u.y = fbits(t[k4 + 1][sl]);
        u.z = fbits(t[k4 + 2][sl]); u.w = fbits(t[k4 + 3][sl]);
        *(ushort4*)(Xt + (size_t)(b * 256 + s0 + sl) * 1024 + k0 + k4) = u;
    }
}

// ---------------------------------------------------------------------------
// mfma_gemm<EPI>: C[m,n] = sum_k A[m,k]*B[n,k] (both k-contiguous bf16, K=1024)
// 128x128 tile, BK=64, 4 waves, 16x16x32 MFMA.
// EPI=0: C -> bf16 row-major ldc=3072 (Y), LDS-transposed coalesced stores.
// EPI=1: A=Wl (m=oc), B=Ot (n=b*256+s): direct stores out[b][oc][s] = C + bias[oc].
// ---------------------------------------------------------------------------
template <int EPI>
__global__ __launch_bounds__(256) void mfma_gemm(const __bf16* __restrict__ A,
                                                 const __bf16* __restrict__ B,
                                                 void* __restrict__ Cout,
                                                 const float* __restrict__ bias) {
    __shared__ union __align__(16) {
        struct { __bf16 A[128 * 64]; __bf16 B[128 * 64]; } kl;
        __bf16 stY[128][136];
    } sm;

    const int tid  = threadIdx.x;
    const int wave = tid >> 6, lane = tid & 63;
    const int wm = wave & 1, wn = wave >> 1;
    const int m0 = blockIdx.x * 128, n0 = blockIdx.y * 128;

    const int srow = lane >> 3;
    const int lchunk = (lane & 7) ^ srow;

    f32x4 acc[4][4] = {};

    for (int kk = 0; kk < 1024; kk += 64) {
        #pragma unroll
        for (int g4 = 0; g4 < 4; ++g4) {
            const int g = g4 * 4 + wave;
            const int row = g * 8 + srow;
            gload_lds16(A + (((size_t)(m0 + row)) << 10) + kk + lchunk * 8,
                        &sm.kl.A[g * 512]);
            gload_lds16(B + (((size_t)(n0 + row)) << 10) + kk + lchunk * 8,
                        &sm.kl.B[g * 512]);
        }
        __syncthreads();

        #pragma unroll
        for (int t = 0; t < 2; ++t) {
            const int chunk = t * 4 + (lane >> 4);
            bf16x8 af[4], bf[4];
            #pragma unroll
            for (int mi = 0; mi < 4; ++mi) {
                int row = wm * 64 + mi * 16 + (lane & 15);
                af[mi] = *(const bf16x8*)&sm.kl.A[row * 64 + ((chunk ^ (row & 7)) << 3)];
            }
            #pragma unroll
            for (int ni = 0; ni < 4; ++ni) {
                int row = wn * 64 + ni * 16 + (lane & 15);
                bf[ni] = *(const bf16x8*)&sm.kl.B[row * 64 + ((chunk ^ (row & 7)) << 3)];
            }
            #pragma unroll
            for (int mi = 0; mi < 4; ++mi)
                #pragma unroll
                for (int ni = 0; ni < 4; ++ni)
                    acc[mi][ni] = __builtin_amdgcn_mfma_f32_16x16x32_bf16(
                        af[mi], bf[ni], acc[mi][ni], 0, 0, 0);
        }
        __syncthreads();
    }

    const int cl = lane & 15, rq = lane >> 4;

    if (EPI == 0) {
        __syncthreads();
        #pragma unroll
        for (int mi = 0; mi < 4; ++mi)
            #pragma unroll
            for (int ni = 0; ni < 4; ++ni) {
                int row = wm * 64 + mi * 16 + rq * 4;
                int col = wn * 64 + ni * 16 + cl;
                #pragma unroll
                for (int j = 0; j < 4; ++j)
                    sm.stY[row + j][col] = to_bf(acc[mi][ni][j]);
            }
        __syncthreads();
        __bf16* Y = (__bf16*)Cout;
        #pragma unroll
        for (int i = 0; i < 8; ++i) {
            int cid = tid + 256 * i;
            int r = cid >> 4, c8 = (cid & 15) * 8;
            *(bf16x8*)(Y + (size_t)(m0 + r) * 3072 + n0 + c8) =
                *(const bf16x8*)&sm.stY[r][c8];
        }
    } else {
        // direct scatter of C[m=oc][n=b*256+s] into out[b][oc][s] (+bias)
        float* out = (float*)Cout;
        float bia[4][4];
        const int rbase = m0 + wm * 64 + rq * 4;
        #pragma unroll
        for (int mi = 0; mi < 4; ++mi)
            #pragma unroll
            for (int j = 0; j < 4; ++j) bia[mi][j] = bias[rbase + mi * 16 + j];
        const int nbase = n0 + wn * 64 + cl;
        #pragma unroll
        for (int mi = 0; mi < 4; ++mi)
            #pragma unroll
            for (int ni = 0; ni < 4; ++ni) {
                int nn = nbase + ni * 16;
                size_t base = ((size_t)(nn >> 8) << 18) + (nn & 255);
                #pragma unroll
                for (int j = 0; j < 4; ++j) {
                    int oc = rbase + mi * 16 + j;
                    out[base + ((size_t)oc << 8)] = acc[mi][ni][j] + bia[mi][j];
                }
            }
    }
}

// ---------------------------------------------------------------------------
// attn_mfma: 16 waves/block, one token per wave (16 consecutive n of one batch).
// o = (softmax_d(rope(q))*scale · softmax_h(rope(k))^T) · v   via MFMA.
// Output staged through XOR-swizzled LDS -> coalesced 128B row segments of
// Ot[b*256 + s][c],  s=(e&15)*16+h, c=n*4+(e>>4).
// ---------------------------------------------------------------------------
__global__ __launch_bounds__(1024) void attn_mfma(const __bf16* __restrict__ Y,
                                                  __bf16* __restrict__ Ot) {
    __shared__ union __align__(16) {
        __bf16  v[16][1024];      // per-wave v[16 h][64 e]
        ushort4 ost[256][16];     // [s][slot] row-strips (XOR-swizzled slots)
    } sm;

    const int tid  = threadIdx.x;
    const int wave = tid >> 6, lane = tid & 63;
    const int bb = blockIdx.x >> 4;
    const int n0 = (blockIdx.x & 15) * 16;
    const int n  = n0 + wave;
    const int quad = lane >> 4, m = lane & 15;
    const __bf16* Yt = Y + (size_t)(bb * 256 + n) * J3;

    // ---- stage v[16][64] -> LDS (2 wave-level 16B DMA instrs) ----
    #pragma unroll
    for (int p = 0; p < 2; ++p) {
        const int h = p * 8 + (lane >> 3), part = lane & 7;
        gload_lds16(Yt + h * 192 + 128 + part * 8, &sm.v[wave][p * 512]);
    }

    // ---- q,k fragments straight from global: [h=m][d = st*32 + quad*8 + j] ----
    bf16x8 qb[2], kb[2];
    #pragma unroll
    for (int st = 0; st < 2; ++st) {
        qb[st] = *(const bf16x8*)(Yt + m * 192 +      st * 32 + quad * 8);
        kb[st] = *(const bf16x8*)(Yt + m * 192 + 64 + st * 32 + quad * 8);
    }
    float qf[16], kf[16];
    #pragma unroll
    for (int st = 0; st < 2; ++st)
        #pragma unroll
        for (int j = 0; j < 8; ++j) {
            qf[st * 8 + j] = (float)qb[st][j];
            kf[st * 8 + j] = (float)kb[st][j];
        }

    // ---- RoPE: pairs (d, d+32) are lane-local (st=0 vs st=1, same j) ----
    const float fn = (float)n;
    #pragma unroll
    for (int j = 0; j < 8; ++j) {
        const float d  = (float)(quad * 8 + j);
        const float th = fn * __expf(-0.28782313662425572f * d);  // n * 10000^(-d/32)
        const float sn = __sinf(th), cn = __cosf(th);
        float a0 = qf[j], a1 = qf[8 + j];
        qf[j]     = a0 * cn - a1 * sn;
        qf[8 + j] = a1 * cn + a0 * sn;
        float b0 = kf[j], b1 = kf[8 + j];
        kf[j]     = b0 * cn - b1 * sn;
        kf[8 + j] = b1 * cn + b0 * sn;
    }

    // ---- q softmax over d (max-free; |q| small) ----
    float qe[16], ls = 0.f;
    #pragma unroll
    for (int i = 0; i < 16; ++i) { qe[i] = __expf(qf[i]); ls += qe[i]; }
    ls += __shfl_xor(ls, 16);
    ls += __shfl_xor(ls, 32);
    const float qinv = 0.125f * __builtin_amdgcn_rcpf(ls);
    bf16x8 qbh[2];
    #pragma unroll
    for (int st = 0; st < 2; ++st)
        #pragma unroll
        for (int j = 0; j < 8; ++j) qbh[st][j] = to_bf(qe[st * 8 + j] * qinv);

    // ---- k softmax over h (16-lane butterfly per d element) ----
    float ke[16], kc[16];
    #pragma unroll
    for (int i = 0; i < 16; ++i) { ke[i] = __expf(kf[i]); kc[i] = ke[i]; }
    #pragma unroll
    for (int msk = 1; msk <= 8; msk <<= 1)
        #pragma unroll
        for (int i = 0; i < 16; ++i) kc[i] += __shfl_xor(kc[i], msk);
    bf16x8 kbh[2];
    #pragma unroll
    for (int st = 0; st < 2; ++st)
        #pragma unroll
        for (int j = 0; j < 8; ++j)
            kbh[st][j] = to_bf(ke[st * 8 + j] * __builtin_amdgcn_rcpf(kc[st * 8 + j]));

    // ---- S' = k · q^T (C-layout row=h'=quad*4+r, col=h=m) ----
    f32x4 Sp = {0.f, 0.f, 0.f, 0.f};
    Sp = __builtin_amdgcn_mfma_f32_16x16x32_bf16(kbh[0], qbh[0], Sp, 0, 0, 0);
    Sp = __builtin_amdgcn_mfma_f32_16x16x32_bf16(kbh[1], qbh[1], Sp, 0, 0, 0);

    __syncthreads();   // drain v DMA before LDS picks

    f32x4 o4[4];
#if __has_builtin(__builtin_amdgcn_mfma_f32_16x16x16f16)
    // A-frag 16x16x16: A[m][k=quad*4+j] := Sp reg j = S[m][quad*4+j]
    f16x4 af;
    #pragma unroll
    for (int r = 0; r < 4; ++r) af[r] = (_Float16)Sp[r];
    #pragma unroll
    for (int tile = 0; tile < 4; ++tile) {
        f16x4 bv;
        #pragma unroll
        for (int j = 0; j < 4; ++j)
            bv[j] = (_Float16)(float)sm.v[wave][(quad * 4 + j) * 64 + tile * 16 + m];
        f32x4 z = {0.f, 0.f, 0.f, 0.f};
        o4[tile] = __builtin_amdgcn_mfma_f32_16x16x16f16(af, bv, z, 0, 0, 0);
    }
#else
    bf16x8 a2;
    #pragma unroll
    for (int j = 0; j < 8; ++j) {
        int k = quad * 8 + j;
        int src = ((k & 15) >> 2) * 16 + m;
        float v = __shfl(Sp[k & 3], src, 64);
        a2[j] = (quad < 2) ? to_bf(v) : to_bf(0.f);
    }
    #pragma unroll
    for (int tile = 0; tile < 4; ++tile) {
        bf16x8 bv;
        #pragma unroll
        for (int j = 0; j < 8; ++j) {
            int k = quad * 8 + j;
            int kk = (k < 16) ? k : 0;
            bv[j] = sm.v[wave][kk * 64 + tile * 16 + m];
        }
        f32x4 z = {0.f, 0.f, 0.f, 0.f};
        o4[tile] = __builtin_amdgcn_mfma_f32_16x16x32_bf16(a2, bv, z, 0, 0, 0);
    }
#endif

    __syncthreads();   // v dead; reuse LDS as ost

    // ---- stage o row-strips: o[h=quad*4+r][e=tile*16+m]; strip (4 tiles) is
    //      Ot row s=m*16+quad*4+r, local cols wave*4..+3 -> slot=wave (XOR-swz)
    #pragma unroll
    for (int r = 0; r < 4; ++r) {
        const int s = m * 16 + quad * 4 + r;
        const int phys = wave ^ (quad * 4 + r) ^ m;   // wave ^ (s&15) ^ (s>>4)
        ushort4 u;
        u.x = fbits(o4[0][r]); u.y = fbits(o4[1][r]);
        u.z = fbits(o4[2][r]); u.w = fbits(o4[3][r]);
        sm.ost[s][phys] = u;
    }
    __syncthreads();

    // ---- coalesced store: thread -> (row s = tid>>2, 32B segment (tid&3)) ----
    {
        const int row = tid >> 2;
        const int w0  = (tid & 3) * 4;
        ushort4 u4[4];
        #pragma unroll
        for (int j = 0; j < 4; ++j) {
            const int phys = (w0 + j) ^ (row & 15) ^ (row >> 4);
            u4[j] = sm.ost[row][phys];
        }
        __bf16* dst = Ot + (((size_t)(bb * 256 + row)) << 10) + n0 * 4 + w0 * 4;
        u16x8 a = {u4[0].x, u4[0].y, u4[0].z, u4[0].w, u4[1].x, u4[1].y, u4[1].z, u4[1].w};
        u16x8 b = {u4[2].x, u4[2].y, u4[2].z, u4[2].w, u4[3].x, u4[3].y, u4[3].z, u4[3].w};
        *(u16x8*)dst = a;
        *(u16x8*)(dst + 8) = b;
    }
}

// ---------------------------------------------------------------------------
extern "C" void kernel_launch(void* const* d_in, const int* in_sizes, int n_in,
                              void* d_out, int out_size, void* d_ws, size_t ws_size,
                              hipStream_t stream) {
    const float* x     = (const float*)d_in[0];
    const float* w_qkv = (const float*)d_in[1];
    const float* w_lin = (const float*)d_in[2];
    const float* b_lin = (const float*)d_in[3];
    float* out = (float*)d_out;

    char* ws = (char*)d_ws;
    __bf16* Y    = (__bf16*)ws;                               // 96 MiB [16384,3072]
    __bf16* XtOt = (__bf16*)(ws + (size_t)100663296);         // 32 MiB [16384,1024] (Xt then Ot)
    __bf16* Wqb  = (__bf16*)(ws + (size_t)134217728);         // 6 MiB  [3072,1024]
    __bf16* Wlb  = (__bf16*)(ws + (size_t)140509184);         // 2 MiB  [1024,1024]

    cvt_w<<<4096, 256, 0, stream>>>(w_qkv, Wqb, w_lin, Wlb);
    xpose_x<<<dim3(8, 32, 64), 256, 0, stream>>>(x, XtOt);

    mfma_gemm<0><<<dim3(128, 24), 256, 0, stream>>>(XtOt, Wqb, (void*)Y, nullptr);
    attn_mfma<<<1024, 1024, 0, stream>>>(Y, XtOt);            // Xt dead; reuse as Ot
    mfma_gemm<1><<<dim3(8, 128), 256, 0, stream>>>(Wlb, XtOt, (void*)out, b_lin);
}